// Round 7
// baseline (288.043 us; speedup 1.0000x reference)
//
#include <hip/hip_runtime.h>
#include <hip/hip_bf16.h>
#include <stdint.h>

#define BB 2
#define SS 2048
#define DMM 2048
#define HH 16
#define DHH 128

typedef unsigned short u16;
typedef __attribute__((ext_vector_type(8))) short bf16x8;
typedef __attribute__((ext_vector_type(8))) unsigned short u16x8;
typedef __attribute__((ext_vector_type(4))) float f32x4;

#define WAITV(N) asm volatile("s_waitcnt vmcnt(" #N ")" ::: "memory")
#define BARRIER asm volatile("s_barrier" ::: "memory")

__device__ __forceinline__ u16 f2bf(float f) {
  union { float f; uint32_t u; } v; v.f = f;
  return (u16)((v.u + 0x7FFFu + ((v.u >> 16) & 1u)) >> 16);  // RNE
}

__device__ __forceinline__ void stage16(const void* g, void* l) {
  __builtin_amdgcn_global_load_lds(
      (const __attribute__((address_space(1))) void*)g,
      (__attribute__((address_space(3))) void*)l, 16, 0, 0);
}

// ---------------- fused f32 -> bf16 converts (x, w_qkv, w_out) ----------------
__global__ void cvt_bf16_k(const float* __restrict__ s0, u16* __restrict__ d0,
                           const float* __restrict__ s1, u16* __restrict__ d1,
                           const float* __restrict__ s2, u16* __restrict__ d2) {
  int bid = blockIdx.x;
  const float* src; u16* dst; size_t base;
  if (bid < 4096)       { src = s0; dst = d0; base = (size_t)bid; }
  else if (bid < 10240) { src = s1; dst = d1; base = (size_t)(bid - 4096); }
  else                  { src = s2; dst = d2; base = (size_t)(bid - 10240); }
  size_t i = base * 256 + threadIdx.x;
  const float4* p = (const float4*)src + i * 2;
  float4 a = p[0], b = p[1];
  u16x8 v;
  v[0] = f2bf(a.x); v[1] = f2bf(a.y); v[2] = f2bf(a.z); v[3] = f2bf(a.w);
  v[4] = f2bf(b.x); v[5] = f2bf(b.y); v[6] = f2bf(b.z); v[7] = f2bf(b.w);
  *((u16x8*)dst + i) = v;
}

// B-row permutation for MODE 0: LDS row p holds matrix row f(p) so that rope
// pairs (d, d+64) land in the SAME lane as frag pair (nf even, nf odd).
__device__ __forceinline__ int bperm(int p) {
  return ((p >> 5) << 4) + (p & 15) + (((p >> 4) & 1) << 6);
}

// ------------- 128x128-tile GEMM, BK=32, C = A[M][K]*B[N][K]^T -------------
// 4 waves as 2x2, wave tile 64x64. BK=32 -> LDS 32KB/block -> 4-5 blocks/CU
// (occupancy attack: round-6 diagnosis = 45% neither-pipe at 2 blocks/CU).
// T3-minimum prefetch: stage(t+1) issued BEFORE compute(t); counted WAITV(4)
// keeps the 4 prefetch loads in flight across the raw barrier.
// 64B LDS rows: swizzle byte ^= ((r>>1)&3)<<4 -> exact 2-way aliasing (free).
// MODE 0: B rows staged with bperm; epilogue = +bias, per-head rope (fc indexed
//         by HEAD per reference), scatter Q(scaled)/K [bh][s][128], V^T [bh][128][s]
// MODE 1: epilogue = +bias, f32 row-major out
template<int MODE>
__global__ __launch_bounds__(256, 4)
void gemm_bt_k(const u16* __restrict__ A, const u16* __restrict__ Bm,
               const float* __restrict__ bias,
               const float* __restrict__ fcr, const float* __restrict__ fci,
               u16* __restrict__ Qo, u16* __restrict__ Ko, u16* __restrict__ Vto,
               float* __restrict__ Fo,
               int Ndim, int Kdim)
{
  const int tid = threadIdx.x;
  const int lane = tid & 63, w = tid >> 6, g = lane >> 4, c = lane & 15;
  const int bn = blockIdx.x, bm = blockIdx.y;   // default order: bn fast ->
  // round-robin spreads a bm-row's 48 bn over XCDs (3MB B per L2, A shared)

  __shared__ __align__(16) u16 As[2][128 * 32];
  __shared__ __align__(16) u16 Bs[2][128 * 32];

  const int wrow = (w >> 1) * 64;
  const int wcol = (w & 1) * 64;

  f32x4 acc[4][4] = {};

  const char* Abase = (const char*)A + ((long)bm * 128) * Kdim * 2;
  const char* Bbase = (const char*)Bm + ((long)bn * 128) * Kdim * 2;

  // 2 A-loads + 2 B-loads per thread per tile (16B each), linear LDS dest +
  // inverse-swizzled (and for MODE 0 B: inverse-permuted) global source
  auto stage_tile = [&](int kb, int buf) {
    #pragma unroll
    for (int i = 0; i < 2; ++i) {
      int off = i * 4096 + tid * 16;
      int r = off >> 6, cb = off & 63;
      int cbs = cb ^ (((r >> 1) & 3) << 4);
      stage16(Abase + ((long)r * Kdim + kb) * 2 + cbs, (char*)As[buf] + off);
    }
    #pragma unroll
    for (int i = 0; i < 2; ++i) {
      int off = i * 4096 + tid * 16;
      int r = off >> 6, cb = off & 63;
      int cbs = cb ^ (((r >> 1) & 3) << 4);
      int rg = (MODE == 0) ? bperm(r) : r;
      stage16(Bbase + ((long)rg * Kdim + kb) * 2 + cbs, (char*)Bs[buf] + off);
    }
  };

  stage_tile(0, 0);
  WAITV(0);
  BARRIER;

  const int nt = Kdim >> 5;
  for (int t = 0; t < nt; ++t) {
    const int cur = t & 1;
    if (t + 1 < nt) { stage_tile((t + 1) << 5, cur ^ 1); WAITV(4); }
    else            { WAITV(0); }

    bf16x8 af[4], bfr[4];
    #pragma unroll
    for (int mf = 0; mf < 4; ++mf) {
      int r = wrow + mf * 16 + c;
      int ab = (r << 6) + ((g << 4) ^ (((r >> 1) & 3) << 4));
      af[mf] = *(const bf16x8*)((const char*)As[cur] + ab);
    }
    #pragma unroll
    for (int nf = 0; nf < 4; ++nf) {
      int r = wcol + nf * 16 + c;
      int ab = (r << 6) + ((g << 4) ^ (((r >> 1) & 3) << 4));
      bfr[nf] = *(const bf16x8*)((const char*)Bs[cur] + ab);
    }
    #pragma unroll
    for (int mf = 0; mf < 4; ++mf)
      #pragma unroll
      for (int nf = 0; nf < 4; ++nf)
        acc[mf][nf] = __builtin_amdgcn_mfma_f32_16x16x32_bf16(af[mf], bfr[nf], acc[mf][nf], 0, 0, 0);
    BARRIER;   // readers of buf done -> next iter may overwrite it
  }

  if constexpr (MODE == 1) {
    #pragma unroll
    for (int mf = 0; mf < 4; ++mf)
      #pragma unroll
      for (int nf = 0; nf < 4; ++nf) {
        int col = bn * 128 + wcol + nf * 16 + c;
        float bv = bias[col];
        #pragma unroll
        for (int j = 0; j < 4; ++j) {
          int row = bm * 128 + wrow + mf * 16 + g * 4 + j;
          Fo[(long)row * Ndim + col] = acc[mf][nf][j] + bv;
        }
      }
  } else {
    const int sec = bn >> 4, h = bn & 15, b = bm >> 4;
    if (sec < 2) {
      // Q/K: rope pairs (d, d+64) = frag pair (nf even, nf odd), same lane
      const float scale = (sec == 0) ? 0.08838834764831845f : 1.0f;  // DH^-0.5 in Q
      u16* O = (sec == 0) ? Qo : Ko;
      #pragma unroll
      for (int pe = 0; pe < 2; ++pe) {
        int nfr = pe * 2, nfi = nfr + 1;
        int p = wcol + nfr * 16 + c;          // parity 0 -> real part
        int d = ((p >> 5) << 4) + (p & 15);   // bperm with im-bit 0
        float fr = fcr[h * 64 + d], fi = fci[h * 64 + d];  // per-HEAD angle (ref quirk)
        float bre = bias[bn * 128 + d], bim = bias[bn * 128 + 64 + d];
        #pragma unroll
        for (int mf = 0; mf < 4; ++mf)
          #pragma unroll
          for (int j = 0; j < 4; ++j) {
            int row = bm * 128 + wrow + mf * 16 + g * 4 + j;
            int s = row & (SS - 1);
            float re = acc[mf][nfr][j] + bre;
            float im = acc[mf][nfi][j] + bim;
            long base = (((long)(b * HH + h)) * SS + s) * DHH;
            O[base + d]      = f2bf((re * fr - im * fi) * scale);
            O[base + 64 + d] = f2bf((re * fi + im * fr) * scale);
          }
      }
    } else {
      // V tile -> transposed layout [bh][d][s] (any col perm fine, use bperm map)
      #pragma unroll
      for (int nf = 0; nf < 4; ++nf) {
        int p = wcol + nf * 16 + c;
        int d = bperm(p);
        float bv = bias[bn * 128 + d];
        #pragma unroll
        for (int mf = 0; mf < 4; ++mf)
          #pragma unroll
          for (int j = 0; j < 4; ++j) {
            int row = bm * 128 + wrow + mf * 16 + g * 4 + j;
            int s = row & (SS - 1);
            Vto[(((long)(b * HH + h)) * DHH + d) * SS + s] = f2bf(acc[mf][nf][j] + bv);
          }
      }
    }
  }
}

// ---------------- causal flash attention, prefetch-pipelined ----------------
// grid: 1024 linear; XCD-chunked: each XCD owns 4 bh (2MB K/V L2-resident),
// qt heavy-first within XCD. block 256 = 4 waves x 16 q-rows, KVBLK=64.
__global__ __launch_bounds__(256)
void attn_k(const u16* __restrict__ Q, const u16* __restrict__ K,
            const u16* __restrict__ Vt, u16* __restrict__ Ao)
{
  const int tid = threadIdx.x;
  const int lane = tid & 63, w = tid >> 6, g = lane >> 4, c = lane & 15;
  const int f = blockIdx.x;
  const int xcd = f & 7, idx = f >> 3;          // idx 0..127
  const int bh = xcd * 4 + (idx & 3);           // 4 bh per XCD
  const int qt = 31 - (idx >> 2);               // heavy tiles first
  const int b = bh >> 4, h = bh & 15;
  const int qbase = qt * 64;

  __shared__ __align__(16) u16 Ks[2][64 * 128];    // rows 256B, XOR-swizzled
  __shared__ __align__(16) u16 Vts[2][128 * 64];   // [dh][kv], rows 128B, swizzled
  __shared__ __align__(16) u16 Ps[4][16 * 64];     // wave-private P, swizzled

  const long head = (long)bh * SS * DHH;
  const int wub = w * 1024;

  auto stage_tile = [&](int t, int buf) {
    const int kvbase = t * 64;
    #pragma unroll
    for (int i = 0; i < 4; ++i) {  // K tile 64x128
      int ob = i * 4096 + wub;
      int o_ = ob + (lane << 4);
      int r = o_ >> 8, cb = o_ & 255;
      int cbs = cb ^ ((r & 7) << 4);
      stage16((const char*)(K + head) + (long)(kvbase + r) * 256 + cbs, (char*)Ks[buf] + ob);
    }
    #pragma unroll
    for (int i = 0; i < 4; ++i) {  // Vt tile 128x64
      int ob = i * 4096 + wub;
      int o_ = ob + (lane << 4);
      int r = o_ >> 7, cb = o_ & 127;
      int cbs = cb ^ ((r & 7) << 4);
      stage16((const char*)(Vt + head) + (long)r * (SS * 2) + kvbase * 2 + cbs, (char*)Vts[buf] + ob);
    }
  };

  bf16x8 qf[4];  // Q rows already scaled by DH^-0.5
  {
    const u16* qp = Q + head + (long)(qbase + w * 16 + c) * DHH + g * 8;
    #pragma unroll
    for (int kc = 0; kc < 4; ++kc) qf[kc] = *(const bf16x8*)(qp + kc * 32);
  }

  f32x4 o[8] = {};
  float m[4], l[4];
  #pragma unroll
  for (int j = 0; j < 4; ++j) { m[j] = -INFINITY; l[j] = 0.f; }

  stage_tile(0, 0);
  WAITV(0);
  BARRIER;

  for (int t = 0; t <= qt; ++t) {
    const int cur = t & 1;
    if (t < qt) { stage_tile(t + 1, cur ^ 1); WAITV(8); }
    else        { WAITV(0); }

    // S = Q K^T (per wave: 16 q-rows x 64 kv)
    f32x4 sf[4];
    __builtin_amdgcn_s_setprio(1);
    #pragma unroll
    for (int nf = 0; nf < 4; ++nf) {
      f32x4 s = {0.f, 0.f, 0.f, 0.f};
      #pragma unroll
      for (int kc = 0; kc < 4; ++kc) {
        int r = nf * 16 + c;
        int ab = (r << 8) + kc * 64 + (g << 4);
        ab ^= (r & 7) << 4;
        bf16x8 kf = *(const bf16x8*)((const char*)Ks[cur] + ab);
        s = __builtin_amdgcn_mfma_f32_16x16x32_bf16(qf[kc], kf, s, 0, 0, 0);
      }
      sf[nf] = s;
    }
    __builtin_amdgcn_s_setprio(0);

    if (t == qt) {  // diagonal tile: strict causal mask
      #pragma unroll
      for (int nf = 0; nf < 4; ++nf)
        #pragma unroll
        for (int j = 0; j < 4; ++j)
          if (nf * 16 + c > w * 16 + g * 4 + j) sf[nf][j] = -INFINITY;
    }

    // online softmax (rows live on 16-lane groups, reduce over lane&15)
    float mn[4], cf[4], rs[4];
    #pragma unroll
    for (int j = 0; j < 4; ++j) {
      float v = fmaxf(fmaxf(sf[0][j], sf[1][j]), fmaxf(sf[2][j], sf[3][j]));
      v = fmaxf(v, __shfl_xor(v, 1));
      v = fmaxf(v, __shfl_xor(v, 2));
      v = fmaxf(v, __shfl_xor(v, 4));
      v = fmaxf(v, __shfl_xor(v, 8));
      mn[j] = fmaxf(m[j], v);
      cf[j] = exp2f((m[j] - mn[j]) * 1.4426950408889634f);
      m[j] = mn[j];
      rs[j] = 0.f;
    }
    #pragma unroll
    for (int nf = 0; nf < 4; ++nf)
      #pragma unroll
      for (int j = 0; j < 4; ++j) {
        float p = exp2f((sf[nf][j] - mn[j]) * 1.4426950408889634f);
        sf[nf][j] = p;
        rs[j] += p;
      }
    #pragma unroll
    for (int j = 0; j < 4; ++j) {
      float v = rs[j];
      v += __shfl_xor(v, 1); v += __shfl_xor(v, 2);
      v += __shfl_xor(v, 4); v += __shfl_xor(v, 8);
      l[j] = l[j] * cf[j] + v;
    }
    #pragma unroll
    for (int nf = 0; nf < 8; ++nf)
      #pragma unroll
      for (int j = 0; j < 4; ++j)
        o[nf][j] *= cf[j];

    // P -> wave-private LDS (C-layout -> A-layout redistribution)
    #pragma unroll
    for (int nf = 0; nf < 4; ++nf)
      #pragma unroll
      for (int j = 0; j < 4; ++j) {
        int pr = g * 4 + j;
        int ab = (pr << 7) + (nf * 16 + c) * 2;
        ab ^= (pr & 7) << 4;
        *(u16*)((char*)Ps[w] + ab) = f2bf(sf[nf][j]);
      }

    // O += P V
    bf16x8 pf[2];
    #pragma unroll
    for (int kc = 0; kc < 2; ++kc) {
      int ab = (c << 7) + kc * 64 + (g << 4);
      ab ^= (c & 7) << 4;
      pf[kc] = *(const bf16x8*)((const char*)Ps[w] + ab);
    }
    __builtin_amdgcn_s_setprio(1);
    #pragma unroll
    for (int nf = 0; nf < 8; ++nf) {
      #pragma unroll
      for (int kc = 0; kc < 2; ++kc) {
        int r = nf * 16 + c;
        int ab = (r << 7) + kc * 64 + (g << 4);
        ab ^= (r & 7) << 4;
        bf16x8 vf = *(const bf16x8*)((const char*)Vts[cur] + ab);
        o[nf] = __builtin_amdgcn_mfma_f32_16x16x32_bf16(pf[kc], vf, o[nf], 0, 0, 0);
      }
    }
    __builtin_amdgcn_s_setprio(0);
    BARRIER;   // readers of buf done -> next iter may overwrite it
  }

  #pragma unroll
  for (int j = 0; j < 4; ++j) {
    float inv = 1.0f / l[j];
    int row = qbase + w * 16 + g * 4 + j;
    long ob = ((long)(b * SS + row)) * DMM + h * DHH;
    #pragma unroll
    for (int nf = 0; nf < 8; ++nf)
      Ao[ob + nf * 16 + c] = f2bf(o[nf][j] * inv);
  }
}

extern "C" void kernel_launch(void* const* d_in, const int* in_sizes, int n_in,
                              void* d_out, int out_size, void* d_ws, size_t ws_size,
                              hipStream_t stream) {
  const float* x     = (const float*)d_in[0];
  const float* w_qkv = (const float*)d_in[1];
  const float* b_qkv = (const float*)d_in[2];
  const float* w_out = (const float*)d_in[3];
  const float* b_out = (const float*)d_in[4];
  const float* fcr   = (const float*)d_in[5];
  const float* fci   = (const float*)d_in[6];
  // d_in[7] mask: causal triu(k=1), hardcoded in attn_k
  float* outp = (float*)d_out;

  char* ws = (char*)d_ws;               // needs 96 MB
  u16* xb  = (u16*)(ws + 0);            // 16MB x bf16 [4096][2048]
  u16* wqb = (u16*)(ws + (16L << 20));  // 24MB w_qkv bf16 [6144][2048]
  u16* wob = (u16*)(ws + (40L << 20));  // 8MB  w_out bf16 [2048][2048]
  u16* Qb  = (u16*)(ws + (48L << 20));  // 16MB [bh][s][128] (scaled+roped)
  u16* Kb  = (u16*)(ws + (64L << 20));  // 16MB [bh][s][128] (roped)
  u16* Vtb = (u16*)(ws + (80L << 20));  // 16MB [bh][128][s]
  u16* attno = xb;                      // alias: xb dead after GEMM1

  cvt_bf16_k<<<12288, 256, 0, stream>>>(x, xb, w_qkv, wqb, w_out, wob);

  gemm_bt_k<0><<<dim3(48, 32), 256, 0, stream>>>(
      xb, wqb, b_qkv, fcr, fci, Qb, Kb, Vtb, nullptr, 6144, 2048);

  attn_k<<<1024, 256, 0, stream>>>(Qb, Kb, Vtb, attno);

  gemm_bt_k<1><<<dim3(16, 32), 256, 0, stream>>>(
      attno, wob, b_out, nullptr, nullptr, nullptr, nullptr, nullptr, outp,
      2048, 2048);
}

// Round 8
// 260.787 us; speedup vs baseline: 1.1045x; 1.1045x over previous
//
#include <hip/hip_runtime.h>
#include <hip/hip_bf16.h>
#include <stdint.h>

#define BB 2
#define SS 2048
#define DMM 2048
#define HH 16
#define DHH 128

typedef unsigned short u16;
typedef __attribute__((ext_vector_type(8))) short bf16x8;
typedef __attribute__((ext_vector_type(8))) unsigned short u16x8;
typedef __attribute__((ext_vector_type(4))) float f32x4;

#define WAITV(N) asm volatile("s_waitcnt vmcnt(" #N ")" ::: "memory")
#define BARRIER asm volatile("s_barrier" ::: "memory")

__device__ __forceinline__ u16 f2bf(float f) {
  union { float f; uint32_t u; } v; v.f = f;
  return (u16)((v.u + 0x7FFFu + ((v.u >> 16) & 1u)) >> 16);  // RNE
}

__device__ __forceinline__ void stage16(const void* g, void* l) {
  __builtin_amdgcn_global_load_lds(
      (const __attribute__((address_space(1))) void*)g,
      (__attribute__((address_space(3))) void*)l, 16, 0, 0);
}

// ---------------- fused f32 -> bf16 converts (x, w_qkv, w_out) ----------------
__global__ void cvt_bf16_k(const float* __restrict__ s0, u16* __restrict__ d0,
                           const float* __restrict__ s1, u16* __restrict__ d1,
                           const float* __restrict__ s2, u16* __restrict__ d2) {
  int bid = blockIdx.x;
  const float* src; u16* dst; size_t base;
  if (bid < 4096)       { src = s0; dst = d0; base = (size_t)bid; }
  else if (bid < 10240) { src = s1; dst = d1; base = (size_t)(bid - 4096); }
  else                  { src = s2; dst = d2; base = (size_t)(bid - 10240); }
  size_t i = base * 256 + threadIdx.x;
  const float4* p = (const float4*)src + i * 2;
  float4 a = p[0], b = p[1];
  u16x8 v;
  v[0] = f2bf(a.x); v[1] = f2bf(a.y); v[2] = f2bf(a.z); v[3] = f2bf(a.w);
  v[4] = f2bf(b.x); v[5] = f2bf(b.y); v[6] = f2bf(b.z); v[7] = f2bf(b.w);
  *((u16x8*)dst + i) = v;
}

// B-row permutation for MODE 0: LDS row p holds matrix row bperm(p) so rope
// pairs (d, d+64) land in the SAME lane as frag pair (nf even, nf odd).
__device__ __forceinline__ int bperm(int p) {
  return ((p >> 5) << 4) + (p & 15) + (((p >> 4) & 1) << 6);
}

// ------------- 128x128-tile GEMM, BK=64, 512 threads, C = A*B^T -------------
// 8 waves as 4M x 2N (wave tile 32x64, MF2/NF4) -> 4 waves/SIMD at 2 blocks/CU
// (G1 occupancy: R5 ran 1 wave/SIMD/block; the 43% neither-pipe idle was
// scheduler starvation). T3-minimum prefetch: stage(t+1) before compute(t),
// counted WAITV(4) keeps prefetch in flight across the raw barrier.
// MODE 0: B rows staged with bperm; epilogue = +bias, per-head rope (fc indexed
//         by HEAD per reference), scatter Q(scaled)/K [bh][s][128], V^T [bh][128][s]
// MODE 1: epilogue = +bias, f32 row-major out
template<int MODE>
__global__ __launch_bounds__(512, 4)
void gemm_bt_k(const u16* __restrict__ A, const u16* __restrict__ Bm,
               const float* __restrict__ bias,
               const float* __restrict__ fcr, const float* __restrict__ fci,
               u16* __restrict__ Qo, u16* __restrict__ Ko, u16* __restrict__ Vto,
               float* __restrict__ Fo,
               int Ndim, int Kdim)
{
  const int tid = threadIdx.x;
  const int lane = tid & 63, w = tid >> 6, g = lane >> 4, c = lane & 15;
  const int wm = w >> 1, wn = w & 1;
  const int bn = blockIdx.x, bm = blockIdx.y;  // default order (R5-best L2 mix)

  __shared__ __align__(16) u16 As[2][128 * 64];
  __shared__ __align__(16) u16 Bs[2][128 * 64];

  const int wrow = wm * 32;
  const int wcol = wn * 64;

  f32x4 acc[2][4] = {};

  const char* Abase = (const char*)A + ((long)bm * 128) * Kdim * 2;
  const char* Bbase = (const char*)Bm + ((long)bn * 128) * Kdim * 2;

  // 2 A-loads + 2 B-loads per thread per tile (16B each), linear LDS dest +
  // inverse-swizzled (and for MODE 0 B: inverse-permuted) global source
  auto stage_tile = [&](int kb, int buf) {
    #pragma unroll
    for (int i = 0; i < 2; ++i) {
      int off = i * 8192 + tid * 16;
      int r = off >> 7, cb = off & 127;
      int cbs = cb ^ ((r & 7) << 4);
      stage16(Abase + ((long)r * Kdim + kb) * 2 + cbs, (char*)As[buf] + off);
    }
    #pragma unroll
    for (int i = 0; i < 2; ++i) {
      int off = i * 8192 + tid * 16;
      int r = off >> 7, cb = off & 127;
      int cbs = cb ^ ((r & 7) << 4);
      int rg = (MODE == 0) ? bperm(r) : r;
      stage16(Bbase + ((long)rg * Kdim + kb) * 2 + cbs, (char*)Bs[buf] + off);
    }
  };

  stage_tile(0, 0);
  WAITV(0);
  BARRIER;

  const int nt = Kdim >> 6;
  for (int t = 0; t < nt; ++t) {
    const int cur = t & 1;
    if (t + 1 < nt) { stage_tile((t + 1) << 6, cur ^ 1); WAITV(4); }
    else            { WAITV(0); }

    #pragma unroll
    for (int kc = 0; kc < 2; ++kc) {
      bf16x8 af[2], bfr[4];
      #pragma unroll
      for (int mf = 0; mf < 2; ++mf) {
        int r = wrow + mf * 16 + c;
        int ab = (r << 7) + ((kc * 64 + (g << 4)) ^ ((r & 7) << 4));
        af[mf] = *(const bf16x8*)((const char*)As[cur] + ab);
      }
      #pragma unroll
      for (int nf = 0; nf < 4; ++nf) {
        int r = wcol + nf * 16 + c;
        int ab = (r << 7) + ((kc * 64 + (g << 4)) ^ ((r & 7) << 4));
        bfr[nf] = *(const bf16x8*)((const char*)Bs[cur] + ab);
      }
      #pragma unroll
      for (int mf = 0; mf < 2; ++mf)
        #pragma unroll
        for (int nf = 0; nf < 4; ++nf)
          acc[mf][nf] = __builtin_amdgcn_mfma_f32_16x16x32_bf16(af[mf], bfr[nf], acc[mf][nf], 0, 0, 0);
    }
    BARRIER;   // readers of buf done -> next iter may overwrite it
  }

  if constexpr (MODE == 1) {
    #pragma unroll
    for (int mf = 0; mf < 2; ++mf)
      #pragma unroll
      for (int nf = 0; nf < 4; ++nf) {
        int col = bn * 128 + wcol + nf * 16 + c;
        float bv = bias[col];
        #pragma unroll
        for (int j = 0; j < 4; ++j) {
          int row = bm * 128 + wrow + mf * 16 + g * 4 + j;
          Fo[(long)row * Ndim + col] = acc[mf][nf][j] + bv;
        }
      }
  } else {
    const int sec = bn >> 4, h = bn & 15, b = bm >> 4;
    if (sec < 2) {
      // Q/K: rope pairs (d, d+64) = frag pair (nf even, nf odd), same lane
      const float scale = (sec == 0) ? 0.08838834764831845f : 1.0f;  // DH^-0.5 in Q
      u16* O = (sec == 0) ? Qo : Ko;
      #pragma unroll
      for (int pe = 0; pe < 2; ++pe) {
        int nfr = pe * 2, nfi = nfr + 1;
        int p = wcol + nfr * 16 + c;          // parity 0 -> real part
        int d = ((p >> 5) << 4) + (p & 15);   // bperm with im-bit 0
        float fr = fcr[h * 64 + d], fi = fci[h * 64 + d];  // per-HEAD angle (ref quirk)
        float bre = bias[bn * 128 + d], bim = bias[bn * 128 + 64 + d];
        #pragma unroll
        for (int mf = 0; mf < 2; ++mf)
          #pragma unroll
          for (int j = 0; j < 4; ++j) {
            int row = bm * 128 + wrow + mf * 16 + g * 4 + j;
            int s = row & (SS - 1);
            float re = acc[mf][nfr][j] + bre;
            float im = acc[mf][nfi][j] + bim;
            long base = (((long)(b * HH + h)) * SS + s) * DHH;
            O[base + d]      = f2bf((re * fr - im * fi) * scale);
            O[base + 64 + d] = f2bf((re * fi + im * fr) * scale);
          }
      }
    } else {
      // V tile -> transposed layout [bh][d][s] (any col perm fine, use bperm map)
      #pragma unroll
      for (int nf = 0; nf < 4; ++nf) {
        int p = wcol + nf * 16 + c;
        int d = bperm(p);
        float bv = bias[bn * 128 + d];
        #pragma unroll
        for (int mf = 0; mf < 2; ++mf)
          #pragma unroll
          for (int j = 0; j < 4; ++j) {
            int row = bm * 128 + wrow + mf * 16 + g * 4 + j;
            int s = row & (SS - 1);
            Vto[(((long)(b * HH + h)) * DHH + d) * SS + s] = f2bf(acc[mf][nf][j] + bv);
          }
      }
    }
  }
}

// ---------------- causal flash attention, prefetch-pipelined ----------------
// grid: 1024 linear; XCD-chunked: each XCD owns 4 bh (2MB K/V L2-resident),
// qt heavy-first within XCD. block 256 = 4 waves x 16 q-rows, KVBLK=64.
__global__ __launch_bounds__(256)
void attn_k(const u16* __restrict__ Q, const u16* __restrict__ K,
            const u16* __restrict__ Vt, u16* __restrict__ Ao)
{
  const int tid = threadIdx.x;
  const int lane = tid & 63, w = tid >> 6, g = lane >> 4, c = lane & 15;
  const int f = blockIdx.x;
  const int xcd = f & 7, idx = f >> 3;          // idx 0..127
  const int bh = xcd * 4 + (idx & 3);           // 4 bh per XCD
  const int qt = 31 - (idx >> 2);               // heavy tiles first
  const int b = bh >> 4, h = bh & 15;
  const int qbase = qt * 64;

  __shared__ __align__(16) u16 Ks[2][64 * 128];    // rows 256B, XOR-swizzled
  __shared__ __align__(16) u16 Vts[2][128 * 64];   // [dh][kv], rows 128B, swizzled
  __shared__ __align__(16) u16 Ps[4][16 * 64];     // wave-private P, swizzled

  const long head = (long)bh * SS * DHH;
  const int wub = w * 1024;

  auto stage_tile = [&](int t, int buf) {
    const int kvbase = t * 64;
    #pragma unroll
    for (int i = 0; i < 4; ++i) {  // K tile 64x128
      int ob = i * 4096 + wub;
      int o_ = ob + (lane << 4);
      int r = o_ >> 8, cb = o_ & 255;
      int cbs = cb ^ ((r & 7) << 4);
      stage16((const char*)(K + head) + (long)(kvbase + r) * 256 + cbs, (char*)Ks[buf] + ob);
    }
    #pragma unroll
    for (int i = 0; i < 4; ++i) {  // Vt tile 128x64
      int ob = i * 4096 + wub;
      int o_ = ob + (lane << 4);
      int r = o_ >> 7, cb = o_ & 127;
      int cbs = cb ^ ((r & 7) << 4);
      stage16((const char*)(Vt + head) + (long)r * (SS * 2) + kvbase * 2 + cbs, (char*)Vts[buf] + ob);
    }
  };

  bf16x8 qf[4];  // Q rows already scaled by DH^-0.5
  {
    const u16* qp = Q + head + (long)(qbase + w * 16 + c) * DHH + g * 8;
    #pragma unroll
    for (int kc = 0; kc < 4; ++kc) qf[kc] = *(const bf16x8*)(qp + kc * 32);
  }

  f32x4 o[8] = {};
  float m[4], l[4];
  #pragma unroll
  for (int j = 0; j < 4; ++j) { m[j] = -INFINITY; l[j] = 0.f; }

  stage_tile(0, 0);
  WAITV(0);
  BARRIER;

  for (int t = 0; t <= qt; ++t) {
    const int cur = t & 1;
    if (t < qt) { stage_tile(t + 1, cur ^ 1); WAITV(8); }
    else        { WAITV(0); }

    // S = Q K^T (per wave: 16 q-rows x 64 kv)
    f32x4 sf[4];
    __builtin_amdgcn_s_setprio(1);
    #pragma unroll
    for (int nf = 0; nf < 4; ++nf) {
      f32x4 s = {0.f, 0.f, 0.f, 0.f};
      #pragma unroll
      for (int kc = 0; kc < 4; ++kc) {
        int r = nf * 16 + c;
        int ab = (r << 8) + kc * 64 + (g << 4);
        ab ^= (r & 7) << 4;
        bf16x8 kf = *(const bf16x8*)((const char*)Ks[cur] + ab);
        s = __builtin_amdgcn_mfma_f32_16x16x32_bf16(qf[kc], kf, s, 0, 0, 0);
      }
      sf[nf] = s;
    }
    __builtin_amdgcn_s_setprio(0);

    if (t == qt) {  // diagonal tile: strict causal mask
      #pragma unroll
      for (int nf = 0; nf < 4; ++nf)
        #pragma unroll
        for (int j = 0; j < 4; ++j)
          if (nf * 16 + c > w * 16 + g * 4 + j) sf[nf][j] = -INFINITY;
    }

    // online softmax (rows live on 16-lane groups, reduce over lane&15)
    float mn[4], cf[4], rs[4];
    #pragma unroll
    for (int j = 0; j < 4; ++j) {
      float v = fmaxf(fmaxf(sf[0][j], sf[1][j]), fmaxf(sf[2][j], sf[3][j]));
      v = fmaxf(v, __shfl_xor(v, 1));
      v = fmaxf(v, __shfl_xor(v, 2));
      v = fmaxf(v, __shfl_xor(v, 4));
      v = fmaxf(v, __shfl_xor(v, 8));
      mn[j] = fmaxf(m[j], v);
      cf[j] = exp2f((m[j] - mn[j]) * 1.4426950408889634f);
      m[j] = mn[j];
      rs[j] = 0.f;
    }
    #pragma unroll
    for (int nf = 0; nf < 4; ++nf)
      #pragma unroll
      for (int j = 0; j < 4; ++j) {
        float p = exp2f((sf[nf][j] - mn[j]) * 1.4426950408889634f);
        sf[nf][j] = p;
        rs[j] += p;
      }
    #pragma unroll
    for (int j = 0; j < 4; ++j) {
      float v = rs[j];
      v += __shfl_xor(v, 1); v += __shfl_xor(v, 2);
      v += __shfl_xor(v, 4); v += __shfl_xor(v, 8);
      l[j] = l[j] * cf[j] + v;
    }
    #pragma unroll
    for (int nf = 0; nf < 8; ++nf)
      #pragma unroll
      for (int j = 0; j < 4; ++j)
        o[nf][j] *= cf[j];

    // P -> wave-private LDS (C-layout -> A-layout redistribution)
    #pragma unroll
    for (int nf = 0; nf < 4; ++nf)
      #pragma unroll
      for (int j = 0; j < 4; ++j) {
        int pr = g * 4 + j;
        int ab = (pr << 7) + (nf * 16 + c) * 2;
        ab ^= (pr & 7) << 4;
        *(u16*)((char*)Ps[w] + ab) = f2bf(sf[nf][j]);
      }

    // O += P V
    bf16x8 pf[2];
    #pragma unroll
    for (int kc = 0; kc < 2; ++kc) {
      int ab = (c << 7) + kc * 64 + (g << 4);
      ab ^= (c & 7) << 4;
      pf[kc] = *(const bf16x8*)((const char*)Ps[w] + ab);
    }
    __builtin_amdgcn_s_setprio(1);
    #pragma unroll
    for (int nf = 0; nf < 8; ++nf) {
      #pragma unroll
      for (int kc = 0; kc < 2; ++kc) {
        int r = nf * 16 + c;
        int ab = (r << 7) + kc * 64 + (g << 4);
        ab ^= (r & 7) << 4;
        bf16x8 vf = *(const bf16x8*)((const char*)Vts[cur] + ab);
        o[nf] = __builtin_amdgcn_mfma_f32_16x16x32_bf16(pf[kc], vf, o[nf], 0, 0, 0);
      }
    }
    __builtin_amdgcn_s_setprio(0);
    BARRIER;   // readers of buf done -> next iter may overwrite it
  }

  #pragma unroll
  for (int j = 0; j < 4; ++j) {
    float inv = 1.0f / l[j];
    int row = qbase + w * 16 + g * 4 + j;
    long ob = ((long)(b * SS + row)) * DMM + h * DHH;
    #pragma unroll
    for (int nf = 0; nf < 8; ++nf)
      Ao[ob + nf * 16 + c] = f2bf(o[nf][j] * inv);
  }
}

extern "C" void kernel_launch(void* const* d_in, const int* in_sizes, int n_in,
                              void* d_out, int out_size, void* d_ws, size_t ws_size,
                              hipStream_t stream) {
  const float* x     = (const float*)d_in[0];
  const float* w_qkv = (const float*)d_in[1];
  const float* b_qkv = (const float*)d_in[2];
  const float* w_out = (const float*)d_in[3];
  const float* b_out = (const float*)d_in[4];
  const float* fcr   = (const float*)d_in[5];
  const float* fci   = (const float*)d_in[6];
  // d_in[7] mask: causal triu(k=1), hardcoded in attn_k
  float* outp = (float*)d_out;

  char* ws = (char*)d_ws;               // needs 96 MB
  u16* xb  = (u16*)(ws + 0);            // 16MB x bf16 [4096][2048]
  u16* wqb = (u16*)(ws + (16L << 20));  // 24MB w_qkv bf16 [6144][2048]
  u16* wob = (u16*)(ws + (40L << 20));  // 8MB  w_out bf16 [2048][2048]
  u16* Qb  = (u16*)(ws + (48L << 20));  // 16MB [bh][s][128] (scaled+roped)
  u16* Kb  = (u16*)(ws + (64L << 20));  // 16MB [bh][s][128] (roped)
  u16* Vtb = (u16*)(ws + (80L << 20));  // 16MB [bh][128][s]
  u16* attno = xb;                      // alias: xb dead after GEMM1

  cvt_bf16_k<<<12288, 256, 0, stream>>>(x, xb, w_qkv, wqb, w_out, wob);

  gemm_bt_k<0><<<dim3(48, 32), 512, 0, stream>>>(
      xb, wqb, b_qkv, fcr, fci, Qb, Kb, Vtb, nullptr, 6144, 2048);

  attn_k<<<1024, 256, 0, stream>>>(Qb, Kb, Vtb, attno);

  gemm_bt_k<1><<<dim3(16, 32), 512, 0, stream>>>(
      attno, wob, b_out, nullptr, nullptr, nullptr, nullptr, nullptr, outp,
      2048, 2048);
}